// Round 2
// baseline (248.844 us; speedup 1.0000x reference)
//
#include <hip/hip_runtime.h>
#include <stdint.h>

// SFFM — inputs [L=4,B=8,C=256,H=64,W=64] float32, W [256,256] float32.
//   gap    = mean(inputs, axis=(3,4))             -> [L,B,C]
//   scores = gap @ W^T                            -> [L,B,C]
//   attn   = softmax over L                       -> [L,B,C]
//   out    = inputs * attn[:,:,:,None,None]
//
// 3-kernel structure (v2.1):
//   K1: GAP (one block per channel, coalesced float4 reads)        ~128 MiB read
//   K2: attention — one block per (b,d), computes ALL 4 layers'
//       attn at once (no 4x recompute, no per-streaming-block preamble)
//   K3: pure barrier-free stream-scale: scalar attn broadcast,
//       nontemporal stores (via native clang vector type — HIP float4
//       is a class and the builtin rejects it) so the 128 MiB write
//       stream doesn't evict the L3-resident input before its 2nd read.
//
// Channel index convention: ch = (l*B + b)*C + d.

#define L_DIM 4
#define B_DIM 8
#define C_DIM 256
#define HW    4096                      // 64*64 per (l,b,c) channel
#define F4_PER_CH (HW / 4)              // 1024 float4 per channel
#define NCH   (L_DIM * B_DIM * C_DIM)   // 8192 channels
#define NBD   (B_DIM * C_DIM)           // 2048 (b,d) pairs

typedef float nfloat4 __attribute__((ext_vector_type(4)));  // native vec for nt-store

// ---- Kernel 1: GAP. One block (256 threads) per channel. ----
__global__ __launch_bounds__(256) void gap_kernel(
        const float4* __restrict__ in, float* __restrict__ gap) {
    const int ch = blockIdx.x;
    const float4* base = in + (size_t)ch * F4_PER_CH;
    float s = 0.0f;
    #pragma unroll
    for (int k = 0; k < 4; ++k) {
        float4 p = base[threadIdx.x + k * 256];
        s += (p.x + p.y) + (p.z + p.w);
    }
    #pragma unroll
    for (int off = 32; off > 0; off >>= 1)
        s += __shfl_down(s, off, 64);
    __shared__ float wsum[4];
    const int wave = threadIdx.x >> 6;
    const int lane = threadIdx.x & 63;
    if (lane == 0) wsum[wave] = s;
    __syncthreads();
    if (threadIdx.x == 0) {
        gap[ch] = (wsum[0] + wsum[1] + wsum[2] + wsum[3]) * (1.0f / (float)HW);
    }
}

// ---- Kernel 2: attention. One block per (b,d); writes attn for all 4 l. ----
__global__ __launch_bounds__(256) void attn_kernel(
        const float* __restrict__ gap, const float* __restrict__ Wf,
        float* __restrict__ attn) {
    const int bid = blockIdx.x;          // b*C + d
    const int d   = bid & (C_DIM - 1);
    const int b   = bid >> 8;
    const int c   = threadIdx.x;

    const float w = Wf[(size_t)d * C_DIM + c];          // coalesced row read
    float p0 = gap[(0 * B_DIM + b) * C_DIM + c] * w;
    float p1 = gap[(1 * B_DIM + b) * C_DIM + c] * w;
    float p2 = gap[(2 * B_DIM + b) * C_DIM + c] * w;
    float p3 = gap[(3 * B_DIM + b) * C_DIM + c] * w;

    #pragma unroll
    for (int off = 32; off > 0; off >>= 1) {
        p0 += __shfl_down(p0, off, 64);
        p1 += __shfl_down(p1, off, 64);
        p2 += __shfl_down(p2, off, 64);
        p3 += __shfl_down(p3, off, 64);
    }
    __shared__ float part[4][4];   // [wave][l']
    const int wave = threadIdx.x >> 6;
    const int lane = threadIdx.x & 63;
    if (lane == 0) {
        part[wave][0] = p0; part[wave][1] = p1;
        part[wave][2] = p2; part[wave][3] = p3;
    }
    __syncthreads();
    if (threadIdx.x < 4) {
        const float s0 = part[0][0] + part[1][0] + part[2][0] + part[3][0];
        const float s1 = part[0][1] + part[1][1] + part[2][1] + part[3][1];
        const float s2 = part[0][2] + part[1][2] + part[2][2] + part[3][2];
        const float s3 = part[0][3] + part[1][3] + part[2][3] + part[3][3];
        const float m  = fmaxf(fmaxf(s0, s1), fmaxf(s2, s3));
        const float e0 = __expf(s0 - m), e1 = __expf(s1 - m);
        const float e2 = __expf(s2 - m), e3 = __expf(s3 - m);
        const float inv = 1.0f / (e0 + e1 + e2 + e3);
        const int   l   = threadIdx.x;
        const float el  = (l == 0) ? e0 : (l == 1) ? e1 : (l == 2) ? e2 : e3;
        attn[(l * B_DIM + b) * C_DIM + d] = el * inv;
    }
}

// ---- Kernel 3: pure stream-scale. One block per channel, no barriers. ----
__global__ __launch_bounds__(256) void scale_kernel(
        const float4* __restrict__ in, const float* __restrict__ attn,
        float4* __restrict__ out) {
    const int ch = blockIdx.x;
    const float a = attn[ch];            // uniform -> scalar load, broadcast
    const float4* src = in + (size_t)ch * F4_PER_CH;
    nfloat4*      dst = (nfloat4*)(out + (size_t)ch * F4_PER_CH);
    #pragma unroll
    for (int k = 0; k < 4; ++k) {
        float4 p = src[threadIdx.x + k * 256];
        nfloat4 q = { p.x * a, p.y * a, p.z * a, p.w * a };
        __builtin_nontemporal_store(q, &dst[threadIdx.x + k * 256]);
    }
}

extern "C" void kernel_launch(void* const* d_in, const int* in_sizes, int n_in,
                              void* d_out, int out_size, void* d_ws, size_t ws_size,
                              hipStream_t stream) {
    const float4* in_p  = (const float4*)d_in[0];
    const float*  W_p   = (const float*)d_in[1];
    float4*       out_p = (float4*)d_out;

    float* gap  = (float*)d_ws;                  // 8192 floats
    float* attn = (float*)d_ws + NCH;            // 8192 floats

    gap_kernel  <<<NCH, 256, 0, stream>>>(in_p, gap);
    attn_kernel <<<NBD, 256, 0, stream>>>(gap, W_p, attn);
    scale_kernel<<<NCH, 256, 0, stream>>>(in_p, attn, out_p);
}